// Round 2
// baseline (264.626 us; speedup 1.0000x reference)
//
#include <hip/hip_runtime.h>
#include <math.h>

// STGCN layer: N=50000, E=800000, C_IN=C_OUT=64, T=4, KT=3.
// Round-9: channel-split gather (two sequential half-passes).
//   zero_tw:  zero degree counts; block 0 also builds Bt[o][k] bf16 + bb=bg+bt
//   fill:     bucket edges by dst (fixed-cap CSR) + degree counts
//   prescale: xs[n]=bf16(x[n]*dinv[n]) ([c][t] ushort4); xbp[n][6][64]=bf16 x
//             transposed [t][c] with zero guard rows (t=-1,4)
//   gather:   TWO passes, each over half the channels (touched-line footprint
//             12.8MB vs 25.6MB -> higher XCD-L2 hit rate; round-8 lesson:
//             gather time is invariant to occupancy/in-flight -> limiter is
//             the shared L2-miss path, so cut misses, not latency).
//             Wave per node: lanes 0-31 = even edge, 32-63 = odd edge,
//             channel = HALF*32 + (lane&31); 8 gathers (16 edges) in flight;
//             __shfl_xor(32) combines halves.
//   node:     MFMA GEMM, wave = 16 nodes (4 groups): per ki 8 loads feed 16 MFMAs
// All dense math in bf16 MFMA w/ fp32 accum; aggregation in fp32.

#define CAP 64   // max bucket capacity; Poisson(16) max degree ~45

typedef __attribute__((ext_vector_type(8))) short bf16x8;   // 8 bf16 = 4 VGPRs
typedef __attribute__((ext_vector_type(4))) float f32x4;

__device__ __forceinline__ float bf2f(unsigned short u) {
    union { unsigned int i; float f; } c; c.i = ((unsigned int)u) << 16; return c.f;
}
__device__ __forceinline__ unsigned short f2bf(float f) {
    union { float f; unsigned int i; } c; c.f = f;
    return (unsigned short)((c.i + 0x7FFFu + ((c.i >> 16) & 1u)) >> 16);  // RNE
}

// zero cnt across grid; block 0 additionally packs weights:
// Bt[o][k] (bf16): k<64: Wg[k][o]; k=b*64+c (b=1..3): Wt[o][c][b-1]. bb=bg+bt.
__global__ __launch_bounds__(256) void zero_tw_kernel(unsigned* __restrict__ cnt, int N,
                                                      const float* __restrict__ Wg,
                                                      const float* __restrict__ Wt,
                                                      const float* __restrict__ bg,
                                                      const float* __restrict__ bt,
                                                      unsigned short* __restrict__ Bt,
                                                      float* __restrict__ bb) {
    int n = blockIdx.x * 256 + threadIdx.x;
    if (n < N) cnt[n] = 0u;
    if (blockIdx.x == 0) {
        for (int idx = threadIdx.x; idx < 64 * 256; idx += 256) {
            int o = idx >> 8, k = idx & 255;
            float w;
            if (k < 64) w = Wg[k * 64 + o];
            else { int b = k >> 6, c = k & 63; w = Wt[o * 192 + c * 3 + (b - 1)]; }
            Bt[idx] = f2bf(w);
        }
        if (threadIdx.x < 64) bb[threadIdx.x] = bg[threadIdx.x] + bt[threadIdx.x];
    }
}

__global__ __launch_bounds__(256) void fill_kernel(const int* __restrict__ ei,
                                                   unsigned* __restrict__ cnt,
                                                   int* __restrict__ csr, int E) {
    int e = blockIdx.x * 256 + threadIdx.x;
    if (e >= E) return;
    int s = ei[e];        // row 0: src
    int d = ei[E + e];    // row 1: dst
    unsigned slot = atomicAdd(&cnt[d], 1u);
    if (slot < CAP) csr[(size_t)d * CAP + slot] = s;
}

// One wave per node. lane = channel c; float4 covers t=0..3.
__global__ __launch_bounds__(256) void prescale_kernel(const float* __restrict__ x,
                                                       const unsigned* __restrict__ cnt,
                                                       ushort4* __restrict__ xs,
                                                       unsigned short* __restrict__ xbp,
                                                       int N) {
    int n = (blockIdx.x * 256 + threadIdx.x) >> 6;
    int lane = threadIdx.x & 63;
    if (n >= N) return;
    float di = rsqrtf((float)cnt[n] + 1.0f);
    float4 v = ((const float4*)x)[(size_t)n * 64 + lane];
    ushort4 sv;
    sv.x = f2bf(v.x * di); sv.y = f2bf(v.y * di);
    sv.z = f2bf(v.z * di); sv.w = f2bf(v.w * di);
    xs[(size_t)n * 64 + lane] = sv;
    unsigned short* xb = xbp + (size_t)n * 384;
    xb[lane]           = 0;          // t = -1 guard
    xb[64 + lane]      = f2bf(v.x);  // t = 0
    xb[128 + lane]     = f2bf(v.y);
    xb[192 + lane]     = f2bf(v.z);
    xb[256 + lane]     = f2bf(v.w);
    xb[320 + lane]     = 0;          // t = 4 guard
}

// Channel-split gather pass. Wave per node. lanes 0-31 take even edges,
// lanes 32-63 odd edges; each lane covers channel cg = HALF*32 + (lane&31)
// (ushort4 = t0..3). Touched lines per node row: 4 of 8 -> 12.8MB/pass.
// Main loop: 16 edges per iter = 4 int4 idx loads + 8 independent 512B gathers.
template<int HALF>
__global__ __launch_bounds__(256) void gather_half_kernel(const ushort4* __restrict__ xs,
                                                          const int* __restrict__ csr,
                                                          const unsigned* __restrict__ cnt,
                                                          unsigned short* __restrict__ yT,
                                                          int N) {
    int n = (blockIdx.x * 256 + threadIdx.x) >> 6;
    if (n >= N) return;
    int lane = threadIdx.x & 63;
    int half = lane >> 5;            // 0: even edges, 1: odd edges
    int cg = HALF * 32 + (lane & 31);
    unsigned deg = cnt[n];
    int m = (int)deg; if (m > CAP) m = CAP;
    const int* rr = csr + (size_t)n * CAP;
    const int4* r4 = (const int4*)rr;
    float4 acc = make_float4(0.f, 0.f, 0.f, 0.f);

    int i = 0;
    for (; i + 16 <= m; i += 16) {   // 8 gathers in flight, 16 edges
        int q = i >> 2;
        int4 q0 = r4[q], q1 = r4[q + 1], q2 = r4[q + 2], q3 = r4[q + 3];
        int i0 = half ? q0.y : q0.x;
        int i1 = half ? q0.w : q0.z;
        int i2 = half ? q1.y : q1.x;
        int i3 = half ? q1.w : q1.z;
        int i4 = half ? q2.y : q2.x;
        int i5 = half ? q2.w : q2.z;
        int i6 = half ? q3.y : q3.x;
        int i7 = half ? q3.w : q3.z;
        ushort4 g0 = xs[(size_t)i0 * 64 + cg];
        ushort4 g1 = xs[(size_t)i1 * 64 + cg];
        ushort4 g2 = xs[(size_t)i2 * 64 + cg];
        ushort4 g3 = xs[(size_t)i3 * 64 + cg];
        ushort4 g4 = xs[(size_t)i4 * 64 + cg];
        ushort4 g5 = xs[(size_t)i5 * 64 + cg];
        ushort4 g6 = xs[(size_t)i6 * 64 + cg];
        ushort4 g7 = xs[(size_t)i7 * 64 + cg];
        acc.x += ((bf2f(g0.x) + bf2f(g1.x)) + (bf2f(g2.x) + bf2f(g3.x)))
               + ((bf2f(g4.x) + bf2f(g5.x)) + (bf2f(g6.x) + bf2f(g7.x)));
        acc.y += ((bf2f(g0.y) + bf2f(g1.y)) + (bf2f(g2.y) + bf2f(g3.y)))
               + ((bf2f(g4.y) + bf2f(g5.y)) + (bf2f(g6.y) + bf2f(g7.y)));
        acc.z += ((bf2f(g0.z) + bf2f(g1.z)) + (bf2f(g2.z) + bf2f(g3.z)))
               + ((bf2f(g4.z) + bf2f(g5.z)) + (bf2f(g6.z) + bf2f(g7.z)));
        acc.w += ((bf2f(g0.w) + bf2f(g1.w)) + (bf2f(g2.w) + bf2f(g3.w)))
               + ((bf2f(g4.w) + bf2f(g5.w)) + (bf2f(g6.w) + bf2f(g7.w)));
    }
    if (i + 8 <= m) {                // 4 gathers in flight, 8 edges
        int q = i >> 2;
        int4 q0 = r4[q], q1 = r4[q + 1];
        int i0 = half ? q0.y : q0.x;
        int i1 = half ? q0.w : q0.z;
        int i2 = half ? q1.y : q1.x;
        int i3 = half ? q1.w : q1.z;
        ushort4 g0 = xs[(size_t)i0 * 64 + cg];
        ushort4 g1 = xs[(size_t)i1 * 64 + cg];
        ushort4 g2 = xs[(size_t)i2 * 64 + cg];
        ushort4 g3 = xs[(size_t)i3 * 64 + cg];
        acc.x += (bf2f(g0.x) + bf2f(g1.x)) + (bf2f(g2.x) + bf2f(g3.x));
        acc.y += (bf2f(g0.y) + bf2f(g1.y)) + (bf2f(g2.y) + bf2f(g3.y));
        acc.z += (bf2f(g0.z) + bf2f(g1.z)) + (bf2f(g2.z) + bf2f(g3.z));
        acc.w += (bf2f(g0.w) + bf2f(g1.w)) + (bf2f(g2.w) + bf2f(g3.w));
        i += 8;
    }
    if (i + 4 <= m) {                // 2 gathers in flight, 4 edges
        int q = i >> 2;
        int4 q0 = r4[q];
        int i0 = half ? q0.y : q0.x;
        int i1 = half ? q0.w : q0.z;
        ushort4 g0 = xs[(size_t)i0 * 64 + cg];
        ushort4 g1 = xs[(size_t)i1 * 64 + cg];
        acc.x += bf2f(g0.x) + bf2f(g1.x);
        acc.y += bf2f(g0.y) + bf2f(g1.y);
        acc.z += bf2f(g0.z) + bf2f(g1.z);
        acc.w += bf2f(g0.w) + bf2f(g1.w);
        i += 4;
    }
    for (; i < m; i += 2) {          // last <=3 edges, pair steps
        int e = i + half;
        if (e < m) {
            int idx = rr[e];
            ushort4 g = xs[(size_t)idx * 64 + cg];
            acc.x += bf2f(g.x); acc.y += bf2f(g.y);
            acc.z += bf2f(g.z); acc.w += bf2f(g.w);
        }
    }

    // combine even/odd edge partial sums across the half-wave boundary
    acc.x += __shfl_xor(acc.x, 32);
    acc.y += __shfl_xor(acc.y, 32);
    acc.z += __shfl_xor(acc.z, 32);
    acc.w += __shfl_xor(acc.w, 32);

    ushort4 s = xs[(size_t)n * 64 + cg];       // self term (prescaled)
    float di = rsqrtf((float)deg + 1.0f);
    float fx = (bf2f(s.x) + acc.x) * di;
    float fy = (bf2f(s.y) + acc.y) * di;
    float fz = (bf2f(s.z) + acc.z) * di;
    float fw = (bf2f(s.w) + acc.w) * di;

    unsigned short* yp = yT + (size_t)n * 256;
    int t0 = half * 2;                          // lanes<32 write t0,1; >=32 t2,3
    float a = half ? fz : fx;
    float b = half ? fw : fy;
    yp[t0 * 64 + cg]       = f2bf(a);           // 2x64B segments per store
    yp[(t0 + 1) * 64 + cg] = f2bf(b);
}

// MFMA node kernel. Wave = 4 groups x 4 nodes = 16 nodes. Per group: 16 M-rows
// (m = nd*4 + t), K = 256, o = 64 (4 otiles of 16).
// A[(n,t)][k]: k<64 -> yT[n][t][k]; k=b*64+c -> xbp[n][t+b-1][c] (guarded rows).
// A-frag: lane holds A[m=lane&15][k = ki*32 + (lane>>4)*8 + j], 16B contiguous.
// B-frag: lane holds W[k][o = otile*16 + (lane&15)] from Bt[o][k], 16B contiguous.
// C/D: col = lane&15 (=o-idx), row = (lane>>4)*4 + reg -> node +(lane>>4), t = reg.
__global__ __launch_bounds__(256) void node_kernel(const unsigned short* __restrict__ yT,
                                                   const unsigned short* __restrict__ xbp,
                                                   const unsigned short* __restrict__ Bt,
                                                   const float* __restrict__ bb,
                                                   float* __restrict__ out, int N) {
    int wid = (blockIdx.x * 256 + threadIdx.x) >> 6;   // global wave id
    int lane = threadIdx.x & 63;
    int base = wid * 16;                               // first node of this wave
    if (base + 16 > N) return;                         // N % 16 == 0
    int h = lane >> 4;          // quad
    int m = lane & 15;
    int nd = m >> 2, t = m & 3;

    const unsigned short* yp[4];
    const unsigned short* xp[4];
    #pragma unroll
    for (int g = 0; g < 4; ++g) {
        int node = base + g * 4 + nd;
        yp[g] = yT + (size_t)node * 256 + t * 64;
        xp[g] = xbp + (size_t)node * 384 + t * 64;
    }

    f32x4 acc[4][4];
    #pragma unroll
    for (int g = 0; g < 4; ++g)
        #pragma unroll
        for (int ot = 0; ot < 4; ++ot)
            acc[g][ot] = (f32x4){0.f, 0.f, 0.f, 0.f};

    #pragma unroll
    for (int ki = 0; ki < 8; ++ki) {
        int b = ki >> 1;                       // 64-wide K-block
        int c0 = (ki & 1) * 32 + h * 8;        // offset within block
        int kof = ki * 32 + h * 8;
        bf16x8 bf[4];
        #pragma unroll
        for (int ot = 0; ot < 4; ++ot)
            bf[ot] = *(const bf16x8*)(Bt + (size_t)(ot * 16 + m) * 256 + kof);
        bf16x8 af[4];
        #pragma unroll
        for (int g = 0; g < 4; ++g) {
            const unsigned short* ap = (b == 0) ? (yp[g] + c0)
                                                : (xp[g] + (b - 1) * 64 + c0);
            af[g] = *(const bf16x8*)ap;
        }
        #pragma unroll
        for (int g = 0; g < 4; ++g) {
            acc[g][0] = __builtin_amdgcn_mfma_f32_16x16x32_bf16(af[g], bf[0], acc[g][0], 0, 0, 0);
            acc[g][1] = __builtin_amdgcn_mfma_f32_16x16x32_bf16(af[g], bf[1], acc[g][1], 0, 0, 0);
            acc[g][2] = __builtin_amdgcn_mfma_f32_16x16x32_bf16(af[g], bf[2], acc[g][2], 0, 0, 0);
            acc[g][3] = __builtin_amdgcn_mfma_f32_16x16x32_bf16(af[g], bf[3], acc[g][3], 0, 0, 0);
        }
    }

    float4* out4 = (float4*)out;               // out[n][o][t], float4 over t
    #pragma unroll
    for (int g = 0; g < 4; ++g) {
        int nn = base + g * 4 + h;             // output node for this lane
        #pragma unroll
        for (int ot = 0; ot < 4; ++ot) {
            int o = ot * 16 + m;
            float bias = bb[o];
            out4[(size_t)nn * 64 + o] = make_float4(acc[g][ot][0] + bias,
                                                    acc[g][ot][1] + bias,
                                                    acc[g][ot][2] + bias,
                                                    acc[g][ot][3] + bias);
        }
    }
}

extern "C" void kernel_launch(void* const* d_in, const int* in_sizes, int n_in,
                              void* d_out, int out_size, void* d_ws, size_t ws_size,
                              hipStream_t stream) {
    const float* x  = (const float*)d_in[0];
    const int*   ei = (const int*)d_in[1];
    const float* Wg = (const float*)d_in[2];
    const float* bg = (const float*)d_in[3];
    const float* Wt = (const float*)d_in[4];
    const float* bt = (const float*)d_in[5];
    float* out = (float*)d_out;

    int N = in_sizes[0] / 256;   // 50000
    int E = in_sizes[1] / 2;     // 800000

    // workspace layout (256B-aligned):
    size_t off = 0;
    auto alloc = [&](size_t bytes) { size_t o = off; off += (bytes + 255) & ~(size_t)255; return o; };
    char* ws = (char*)d_ws;
    unsigned*       cnt = (unsigned*)(ws + alloc((size_t)N * 4));
    unsigned short* Bt  = (unsigned short*)(ws + alloc(64 * 256 * 2));
    float*          bb  = (float*)(ws + alloc(64 * 4));
    int*            csr = (int*)(ws + alloc((size_t)N * CAP * 4));
    ushort4*        xs  = (ushort4*)(ws + alloc((size_t)N * 256 * 2));
    unsigned short* xbp = (unsigned short*)(ws + alloc((size_t)N * 384 * 2));
    unsigned short* yT  = (unsigned short*)(ws + alloc((size_t)N * 256 * 2));
    // total ~103 MB

    zero_tw_kernel<<<(N + 255) / 256, 256, 0, stream>>>(cnt, N, Wg, Wt, bg, bt, Bt, bb);
    fill_kernel<<<(E + 255) / 256, 256, 0, stream>>>(ei, cnt, csr, E);
    prescale_kernel<<<(N + 3) / 4, 256, 0, stream>>>(x, cnt, xs, xbp, N);
    int gblocks = (N + 3) / 4;                 // wave per node, 12500 blocks/pass
    gather_half_kernel<0><<<gblocks, 256, 0, stream>>>(xs, csr, cnt, yT, N);
    gather_half_kernel<1><<<gblocks, 256, 0, stream>>>(xs, csr, cnt, yT, N);
    int waves = N / 16;                        // 3125
    node_kernel<<<(waves + 3) / 4, 256, 0, stream>>>(yT, xbp, Bt, bb, out, N);
}

// Round 3
// 260.581 us; speedup vs baseline: 1.0155x; 1.0155x over previous
//
#include <hip/hip_runtime.h>
#include <math.h>

// STGCN layer: N=50000, E=800000, C_IN=C_OUT=64, T=4, KT=3.
// Round-10: attack fill (atomic-bound, 55us) + overlap it with streaming.
//   zero_tw:   zero degree counts; block 0 also builds Bt[o][k] bf16 + bb=bg+bt
//   fill_xbp:  fused, two block roles:
//              - fill role (391 blocks): 8 edges/thread, 8 independent
//                predicated atomicAdds in flight, then 8 CSR stores
//                (round-9 PMC: fill VALUBusy 0.4%, 912 GB/s, 14.5G atomics/s
//                 -> test issue-limit vs ~19G/s L2-channel atomic ceiling)
//              - xbp role (12500 blocks): x -> bf16 [t][c] transpose w/ guard
//                rows (cnt-independent half of old prescale; streams ~90MB on
//                fill's idle bandwidth)
//   xs:        xs[n]=bf16(x[n]*dinv[n]) ([c][t] ushort4); needs cnt from fill
//   gather:    round-7 best-measured form (60.0us): wave per TWO nodes,
//              2 int4 idx loads + 8 independent 512B gathers in flight
//              (rounds 8/9 showed gather invariant to MLP and footprint ->
//               shared request-path floor ~60us; leave alone)
//   node:      MFMA GEMM, wave = 16 nodes (4 groups): per ki 8 loads, 16 MFMAs
// All dense math in bf16 MFMA w/ fp32 accum; aggregation in fp32.

#define CAP 64   // max bucket capacity; Poisson(16) max degree ~45

typedef __attribute__((ext_vector_type(8))) short bf16x8;   // 8 bf16 = 4 VGPRs
typedef __attribute__((ext_vector_type(4))) float f32x4;

__device__ __forceinline__ float bf2f(unsigned short u) {
    union { unsigned int i; float f; } c; c.i = ((unsigned int)u) << 16; return c.f;
}
__device__ __forceinline__ unsigned short f2bf(float f) {
    union { float f; unsigned int i; } c; c.f = f;
    return (unsigned short)((c.i + 0x7FFFu + ((c.i >> 16) & 1u)) >> 16);  // RNE
}

// zero cnt across grid; block 0 additionally packs weights:
// Bt[o][k] (bf16): k<64: Wg[k][o]; k=b*64+c (b=1..3): Wt[o][c][b-1]. bb=bg+bt.
__global__ __launch_bounds__(256) void zero_tw_kernel(unsigned* __restrict__ cnt, int N,
                                                      const float* __restrict__ Wg,
                                                      const float* __restrict__ Wt,
                                                      const float* __restrict__ bg,
                                                      const float* __restrict__ bt,
                                                      unsigned short* __restrict__ Bt,
                                                      float* __restrict__ bb) {
    int n = blockIdx.x * 256 + threadIdx.x;
    if (n < N) cnt[n] = 0u;
    if (blockIdx.x == 0) {
        for (int idx = threadIdx.x; idx < 64 * 256; idx += 256) {
            int o = idx >> 8, k = idx & 255;
            float w;
            if (k < 64) w = Wg[k * 64 + o];
            else { int b = k >> 6, c = k & 63; w = Wt[o * 192 + c * 3 + (b - 1)]; }
            Bt[idx] = f2bf(w);
        }
        if (threadIdx.x < 64) bb[threadIdx.x] = bg[threadIdx.x] + bt[threadIdx.x];
    }
}

// Fused fill + xbp. Block roles split by blockIdx:
//  [0, FB):       fill — 8 edges/thread (rounds k: e = t + k*FB*256, coalesced
//                 per round), 8 independent atomics, then 8 CSR stores.
//  [FB, FB+XB):   xbp — wave per node, lane = channel; 6 ushort rows with
//                 zero guards at t=-1 and t=4.
__global__ __launch_bounds__(256) void fill_xbp_kernel(const int* __restrict__ ei,
                                                       unsigned* __restrict__ cnt,
                                                       int* __restrict__ csr, int E,
                                                       const float* __restrict__ x,
                                                       unsigned short* __restrict__ xbp,
                                                       int N, int FB) {
    if ((int)blockIdx.x < FB) {
        int t = blockIdx.x * 256 + threadIdx.x;
        int stride = FB * 256;
        int s[8]; int d[8]; unsigned slot[8];
        #pragma unroll
        for (int k = 0; k < 8; ++k) {
            int e = t + k * stride;
            bool v = (e < E);
            s[k] = v ? ei[e] : -1;       // row 0: src
            d[k] = v ? ei[E + e] : 0;    // row 1: dst
        }
        #pragma unroll
        for (int k = 0; k < 8; ++k)
            slot[k] = (s[k] >= 0) ? atomicAdd(&cnt[d[k]], 1u) : 0u;
        #pragma unroll
        for (int k = 0; k < 8; ++k)
            if (s[k] >= 0 && slot[k] < CAP)
                csr[(size_t)d[k] * CAP + slot[k]] = s[k];
    } else {
        int bid = blockIdx.x - FB;
        int n = (bid * 256 + threadIdx.x) >> 6;
        int lane = threadIdx.x & 63;
        if (n >= N) return;
        float4 v = ((const float4*)x)[(size_t)n * 64 + lane];
        unsigned short* xb = xbp + (size_t)n * 384;
        xb[lane]           = 0;          // t = -1 guard
        xb[64 + lane]      = f2bf(v.x);  // t = 0
        xb[128 + lane]     = f2bf(v.y);
        xb[192 + lane]     = f2bf(v.z);
        xb[256 + lane]     = f2bf(v.w);
        xb[320 + lane]     = 0;          // t = 4 guard
    }
}

// xs[n][c] = bf16(x[n][c][:] * dinv[n]) as ushort4 (t0..3). Needs final cnt.
__global__ __launch_bounds__(256) void xs_kernel(const float* __restrict__ x,
                                                 const unsigned* __restrict__ cnt,
                                                 ushort4* __restrict__ xs, int N) {
    int n = (blockIdx.x * 256 + threadIdx.x) >> 6;
    int lane = threadIdx.x & 63;
    if (n >= N) return;
    float di = rsqrtf((float)cnt[n] + 1.0f);
    float4 v = ((const float4*)x)[(size_t)n * 64 + lane];
    ushort4 sv;
    sv.x = f2bf(v.x * di); sv.y = f2bf(v.y * di);
    sv.z = f2bf(v.z * di); sv.w = f2bf(v.w * di);
    xs[(size_t)n * 64 + lane] = sv;
}

// Wave per TWO nodes; lane = channel c (ushort4 = t0..3). Interleaved inner
// loop: 2 int4 index loads + 8 independent 512B gathers in flight per iter.
__global__ __launch_bounds__(256) void gather_kernel(const ushort4* __restrict__ xs,
                                                     const int* __restrict__ csr,
                                                     const unsigned* __restrict__ cnt,
                                                     unsigned short* __restrict__ yT,
                                                     int N) {
    int w = (blockIdx.x * 256 + threadIdx.x) >> 6;
    int lane = threadIdx.x & 63;
    int n0 = w * 2;
    if (n0 >= N) return;
    int n1 = n0 + 1;                           // N even
    unsigned deg0 = cnt[n0], deg1 = cnt[n1];
    int m0 = (int)deg0; if (m0 > CAP) m0 = CAP;
    int m1 = (int)deg1; if (m1 > CAP) m1 = CAP;
    const int4* r40 = (const int4*)(csr + (size_t)n0 * CAP);
    const int4* r41 = (const int4*)(csr + (size_t)n1 * CAP);
    ushort4 s0 = xs[(size_t)n0 * 64 + lane];
    ushort4 s1 = xs[(size_t)n1 * 64 + lane];
    float4 acc0 = make_float4(bf2f(s0.x), bf2f(s0.y), bf2f(s0.z), bf2f(s0.w));
    float4 acc1 = make_float4(bf2f(s1.x), bf2f(s1.y), bf2f(s1.z), bf2f(s1.w));

    int mc = (m0 < m1 ? m0 : m1) & ~3;
    int i = 0;
    for (; i < mc; i += 4) {                   // interleaved: 8 gathers in flight
        int4 a4 = r40[i >> 2];
        int4 b4 = r41[i >> 2];
        ushort4 a = xs[(size_t)a4.x * 64 + lane];
        ushort4 b = xs[(size_t)a4.y * 64 + lane];
        ushort4 c = xs[(size_t)a4.z * 64 + lane];
        ushort4 d = xs[(size_t)a4.w * 64 + lane];
        ushort4 e = xs[(size_t)b4.x * 64 + lane];
        ushort4 f = xs[(size_t)b4.y * 64 + lane];
        ushort4 g = xs[(size_t)b4.z * 64 + lane];
        ushort4 h = xs[(size_t)b4.w * 64 + lane];
        acc0.x += (bf2f(a.x) + bf2f(b.x)) + (bf2f(c.x) + bf2f(d.x));
        acc0.y += (bf2f(a.y) + bf2f(b.y)) + (bf2f(c.y) + bf2f(d.y));
        acc0.z += (bf2f(a.z) + bf2f(b.z)) + (bf2f(c.z) + bf2f(d.z));
        acc0.w += (bf2f(a.w) + bf2f(b.w)) + (bf2f(c.w) + bf2f(d.w));
        acc1.x += (bf2f(e.x) + bf2f(f.x)) + (bf2f(g.x) + bf2f(h.x));
        acc1.y += (bf2f(e.y) + bf2f(f.y)) + (bf2f(g.y) + bf2f(h.y));
        acc1.z += (bf2f(e.z) + bf2f(f.z)) + (bf2f(g.z) + bf2f(h.z));
        acc1.w += (bf2f(e.w) + bf2f(f.w)) + (bf2f(g.w) + bf2f(h.w));
    }
    int j = i;
    for (; i + 4 <= m0; i += 4) {              // node0 remainder quads
        int4 a4 = r40[i >> 2];
        ushort4 a = xs[(size_t)a4.x * 64 + lane];
        ushort4 b = xs[(size_t)a4.y * 64 + lane];
        ushort4 c = xs[(size_t)a4.z * 64 + lane];
        ushort4 d = xs[(size_t)a4.w * 64 + lane];
        acc0.x += (bf2f(a.x) + bf2f(b.x)) + (bf2f(c.x) + bf2f(d.x));
        acc0.y += (bf2f(a.y) + bf2f(b.y)) + (bf2f(c.y) + bf2f(d.y));
        acc0.z += (bf2f(a.z) + bf2f(b.z)) + (bf2f(c.z) + bf2f(d.z));
        acc0.w += (bf2f(a.w) + bf2f(b.w)) + (bf2f(c.w) + bf2f(d.w));
    }
    for (; i < m0; ++i) {
        int s = ((const int*)r40)[i];
        ushort4 a = xs[(size_t)s * 64 + lane];
        acc0.x += bf2f(a.x); acc0.y += bf2f(a.y);
        acc0.z += bf2f(a.z); acc0.w += bf2f(a.w);
    }
    for (; j + 4 <= m1; j += 4) {              // node1 remainder quads
        int4 b4 = r41[j >> 2];
        ushort4 e = xs[(size_t)b4.x * 64 + lane];
        ushort4 f = xs[(size_t)b4.y * 64 + lane];
        ushort4 g = xs[(size_t)b4.z * 64 + lane];
        ushort4 h = xs[(size_t)b4.w * 64 + lane];
        acc1.x += (bf2f(e.x) + bf2f(f.x)) + (bf2f(g.x) + bf2f(h.x));
        acc1.y += (bf2f(e.y) + bf2f(f.y)) + (bf2f(g.y) + bf2f(h.y));
        acc1.z += (bf2f(e.z) + bf2f(f.z)) + (bf2f(g.z) + bf2f(h.z));
        acc1.w += (bf2f(e.w) + bf2f(f.w)) + (bf2f(g.w) + bf2f(h.w));
    }
    for (; j < m1; ++j) {
        int s = ((const int*)r41)[j];
        ushort4 e = xs[(size_t)s * 64 + lane];
        acc1.x += bf2f(e.x); acc1.y += bf2f(e.y);
        acc1.z += bf2f(e.z); acc1.w += bf2f(e.w);
    }

    float di0 = rsqrtf((float)deg0 + 1.0f);
    float di1 = rsqrtf((float)deg1 + 1.0f);
    unsigned short* yp0 = yT + (size_t)n0 * 256;
    unsigned short* yp1 = yT + (size_t)n1 * 256;
    yp0[lane]       = f2bf(acc0.x * di0);      // coalesced 128B rows
    yp0[64 + lane]  = f2bf(acc0.y * di0);
    yp0[128 + lane] = f2bf(acc0.z * di0);
    yp0[192 + lane] = f2bf(acc0.w * di0);
    yp1[lane]       = f2bf(acc1.x * di1);
    yp1[64 + lane]  = f2bf(acc1.y * di1);
    yp1[128 + lane] = f2bf(acc1.z * di1);
    yp1[192 + lane] = f2bf(acc1.w * di1);
}

// MFMA node kernel. Wave = 4 groups x 4 nodes = 16 nodes. Per group: 16 M-rows
// (m = nd*4 + t), K = 256, o = 64 (4 otiles of 16).
// A[(n,t)][k]: k<64 -> yT[n][t][k]; k=b*64+c -> xbp[n][t+b-1][c] (guarded rows).
// A-frag: lane holds A[m=lane&15][k = ki*32 + (lane>>4)*8 + j], 16B contiguous.
// B-frag: lane holds W[k][o = otile*16 + (lane&15)] from Bt[o][k], 16B contiguous.
// C/D: col = lane&15 (=o-idx), row = (lane>>4)*4 + reg -> node +(lane>>4), t = reg.
__global__ __launch_bounds__(256) void node_kernel(const unsigned short* __restrict__ yT,
                                                   const unsigned short* __restrict__ xbp,
                                                   const unsigned short* __restrict__ Bt,
                                                   const float* __restrict__ bb,
                                                   float* __restrict__ out, int N) {
    int wid = (blockIdx.x * 256 + threadIdx.x) >> 6;   // global wave id
    int lane = threadIdx.x & 63;
    int base = wid * 16;                               // first node of this wave
    if (base + 16 > N) return;                         // N % 16 == 0
    int h = lane >> 4;          // quad
    int m = lane & 15;
    int nd = m >> 2, t = m & 3;

    const unsigned short* yp[4];
    const unsigned short* xp[4];
    #pragma unroll
    for (int g = 0; g < 4; ++g) {
        int node = base + g * 4 + nd;
        yp[g] = yT + (size_t)node * 256 + t * 64;
        xp[g] = xbp + (size_t)node * 384 + t * 64;
    }

    f32x4 acc[4][4];
    #pragma unroll
    for (int g = 0; g < 4; ++g)
        #pragma unroll
        for (int ot = 0; ot < 4; ++ot)
            acc[g][ot] = (f32x4){0.f, 0.f, 0.f, 0.f};

    #pragma unroll
    for (int ki = 0; ki < 8; ++ki) {
        int b = ki >> 1;                       // 64-wide K-block
        int c0 = (ki & 1) * 32 + h * 8;        // offset within block
        int kof = ki * 32 + h * 8;
        bf16x8 bf[4];
        #pragma unroll
        for (int ot = 0; ot < 4; ++ot)
            bf[ot] = *(const bf16x8*)(Bt + (size_t)(ot * 16 + m) * 256 + kof);
        bf16x8 af[4];
        #pragma unroll
        for (int g = 0; g < 4; ++g) {
            const unsigned short* ap = (b == 0) ? (yp[g] + c0)
                                                : (xp[g] + (b - 1) * 64 + c0);
            af[g] = *(const bf16x8*)ap;
        }
        #pragma unroll
        for (int g = 0; g < 4; ++g) {
            acc[g][0] = __builtin_amdgcn_mfma_f32_16x16x32_bf16(af[g], bf[0], acc[g][0], 0, 0, 0);
            acc[g][1] = __builtin_amdgcn_mfma_f32_16x16x32_bf16(af[g], bf[1], acc[g][1], 0, 0, 0);
            acc[g][2] = __builtin_amdgcn_mfma_f32_16x16x32_bf16(af[g], bf[2], acc[g][2], 0, 0, 0);
            acc[g][3] = __builtin_amdgcn_mfma_f32_16x16x32_bf16(af[g], bf[3], acc[g][3], 0, 0, 0);
        }
    }

    float4* out4 = (float4*)out;               // out[n][o][t], float4 over t
    #pragma unroll
    for (int g = 0; g < 4; ++g) {
        int nn = base + g * 4 + h;             // output node for this lane
        #pragma unroll
        for (int ot = 0; ot < 4; ++ot) {
            int o = ot * 16 + m;
            float bias = bb[o];
            out4[(size_t)nn * 64 + o] = make_float4(acc[g][ot][0] + bias,
                                                    acc[g][ot][1] + bias,
                                                    acc[g][ot][2] + bias,
                                                    acc[g][ot][3] + bias);
        }
    }
}

extern "C" void kernel_launch(void* const* d_in, const int* in_sizes, int n_in,
                              void* d_out, int out_size, void* d_ws, size_t ws_size,
                              hipStream_t stream) {
    const float* x  = (const float*)d_in[0];
    const int*   ei = (const int*)d_in[1];
    const float* Wg = (const float*)d_in[2];
    const float* bg = (const float*)d_in[3];
    const float* Wt = (const float*)d_in[4];
    const float* bt = (const float*)d_in[5];
    float* out = (float*)d_out;

    int N = in_sizes[0] / 256;   // 50000
    int E = in_sizes[1] / 2;     // 800000

    // workspace layout (256B-aligned):
    size_t off = 0;
    auto alloc = [&](size_t bytes) { size_t o = off; off += (bytes + 255) & ~(size_t)255; return o; };
    char* ws = (char*)d_ws;
    unsigned*       cnt = (unsigned*)(ws + alloc((size_t)N * 4));
    unsigned short* Bt  = (unsigned short*)(ws + alloc(64 * 256 * 2));
    float*          bb  = (float*)(ws + alloc(64 * 4));
    int*            csr = (int*)(ws + alloc((size_t)N * CAP * 4));
    ushort4*        xs  = (ushort4*)(ws + alloc((size_t)N * 256 * 2));
    unsigned short* xbp = (unsigned short*)(ws + alloc((size_t)N * 384 * 2));
    unsigned short* yT  = (unsigned short*)(ws + alloc((size_t)N * 256 * 2));
    // total ~103 MB

    zero_tw_kernel<<<(N + 255) / 256, 256, 0, stream>>>(cnt, N, Wg, Wt, bg, bt, Bt, bb);
    int FB = (E + 2047) / 2048;                // 391 fill blocks (8 edges/thread)
    int XB = (N + 3) / 4;                      // 12500 xbp blocks (wave/node)
    fill_xbp_kernel<<<FB + XB, 256, 0, stream>>>(ei, cnt, csr, E, x, xbp, N, FB);
    xs_kernel<<<(N + 3) / 4, 256, 0, stream>>>(x, cnt, xs, N);
    int gw = (N + 1) / 2;                      // 25000 waves, 2 nodes each
    gather_kernel<<<(gw + 3) / 4, 256, 0, stream>>>(xs, csr, cnt, yT, N);
    int waves = N / 16;                        // 3125
    node_kernel<<<(waves + 3) / 4, 256, 0, stream>>>(yT, xbp, Bt, bb, out, N);
}